// Round 5
// baseline (995.025 us; speedup 1.0000x reference)
//
#include <hip/hip_runtime.h>
#include <hip/hip_bf16.h>

#define N_POINTS   2000000
#define NUM_GRAPHS 16384
#define HID        40
#define SLOPE      0.01f

// Pass A tiling
#define TILE_A     1024
#define NT_A       ((N_POINTS + TILE_A - 1) / TILE_A)   // 1954
#define XES        1152   // padded row stride (dwords) for xeT (chunk-padded idx max 1147)

// Pass C tiling
#define TILE_C     512
#define NT_C       ((N_POINTS + TILE_C - 1) / TILE_C)   // 3907
#define AROW       20     // dwords per bf16 A-staging row (40 bf16)
#define XOS2       516    // dwords per xoT half-pool channel row (%32==4, 16B aligned)

typedef __attribute__((ext_vector_type(8))) short short8;
typedef __attribute__((ext_vector_type(4))) float fx4;

__device__ __forceinline__ float lrelu(float v) { return v > 0.f ? v : SLOPE * v; }
__device__ __forceinline__ int padidx(int p) { return p + ((p >> 5) << 2); }  // +4 dwords per 32-chunk
__device__ __forceinline__ unsigned short f2bf(float f) {
    __hip_bfloat16 h = __float2bfloat16(f);
    return *(unsigned short*)&h;
}
__device__ __forceinline__ float bf2f(unsigned short u) {
    unsigned int v = ((unsigned int)u) << 16;
    return __uint_as_float(v);
}

// ---------------- Pass A: emb FFN (4 pts/thread) + transpose-reduce + optional xe cache ----------------
__global__ __launch_bounds__(256, 2) void k_emb_aggr(
    const float* __restrict__ x, const int* __restrict__ batch,
    const float* __restrict__ We1, const float* __restrict__ We2,
    float* __restrict__ x_aggr, unsigned short* __restrict__ xe_out, int use_xe)
{
    __shared__ __align__(16) float sWe1[3 * HID];
    __shared__ __align__(16) float sWe2T[5 * HID];          // [c][j]
    __shared__ __align__(16) float xeT[5 * XES];            // padded chunk layout
    __shared__ __align__(16) int   sbp[XES];

    int tid = threadIdx.x;
    for (int k = tid; k < 3 * HID; k += 256) sWe1[k] = We1[k];
    for (int k = tid; k < 5 * HID; k += 256) sWe2T[k] = We2[(k % HID) * 5 + k / HID];
    __syncthreads();

    int base = blockIdx.x * TILE_A;

    float x0[4], x1[4], x2[4];
    int bq[4]; bool vq[4];
#pragma unroll
    for (int q = 0; q < 4; ++q) {
        int p = base + q * 256 + tid;
        vq[q] = p < N_POINTS;
        int ic = vq[q] ? p : (N_POINTS - 1);
        x0[q] = x[ic * 3 + 0]; x1[q] = x[ic * 3 + 1]; x2[q] = x[ic * 3 + 2];
        bq[q] = vq[q] ? batch[ic] : -1;
        sbp[padidx(q * 256 + tid)] = bq[q];
    }

    // layer 1: one weight read feeds 4 points
    float h[4][HID];
    const float4* W1r = (const float4*)sWe1;
#pragma unroll
    for (int j4 = 0; j4 < HID / 4; ++j4) {
        float4 wa = W1r[j4], wb = W1r[10 + j4], wc = W1r[20 + j4];
        float wav[4] = {wa.x, wa.y, wa.z, wa.w};
        float wbv[4] = {wb.x, wb.y, wb.z, wb.w};
        float wcv[4] = {wc.x, wc.y, wc.z, wc.w};
#pragma unroll
        for (int k = 0; k < 4; ++k) {
            int j = j4 * 4 + k;
#pragma unroll
            for (int q = 0; q < 4; ++q)
                h[q][j] = lrelu(x0[q] * wav[k] + x1[q] * wbv[k] + x2[q] * wcv[k]);
        }
    }

    // layer 2 + stage + cache store
#pragma unroll
    for (int c = 0; c < 5; ++c) {
        const float4* wr = (const float4*)&sWe2T[c * HID];
        float s[4] = {0.f, 0.f, 0.f, 0.f};
#pragma unroll
        for (int j4 = 0; j4 < HID / 4; ++j4) {
            float4 w = wr[j4];
            float wv[4] = {w.x, w.y, w.z, w.w};
#pragma unroll
            for (int k = 0; k < 4; ++k) {
#pragma unroll
                for (int q = 0; q < 4; ++q) s[q] += h[q][j4 * 4 + k] * wv[k];
            }
        }
#pragma unroll
        for (int q = 0; q < 4; ++q) {
            float v = vq[q] ? lrelu(s[q]) : 0.f;
            xeT[c * XES + padidx(q * 256 + tid)] = v;
            if (use_xe && vq[q]) xe_out[(size_t)c * N_POINTS + base + q * 256 + tid] = f2bf(v);
        }
    }
    __syncthreads();

    // reduce: ch = tid&7 (first 5 valid), chunk = tid>>3 (0..31), 32 pts each
    int ch = tid & 7, chunk = tid >> 3;
    if (ch < 5) {
        float acc = 0.f;
        int cur = sbp[chunk * 36];
#pragma unroll
        for (int g = 0; g < 8; ++g) {
            float4 v4 = *(const float4*)&xeT[ch * XES + chunk * 36 + g * 4];
            int4   n4 = *(const int4*)&sbp[chunk * 36 + g * 4];
            float vv[4] = {v4.x, v4.y, v4.z, v4.w};
            int   nn[4] = {n4.x, n4.y, n4.z, n4.w};
#pragma unroll
            for (int k = 0; k < 4; ++k) {
                if (nn[k] != cur) {
                    if (cur >= 0) atomicAdd(&x_aggr[cur * 5 + ch], acc);
                    cur = nn[k];
                    acc = vv[k];
                } else {
                    acc += vv[k];
                }
            }
        }
        if (cur >= 0) atomicAdd(&x_aggr[cur * 5 + ch], acc);
    }
}

// ---------------- Pass B: per-graph global FFN + fold into W_out1 rows 5..8 ----------------
__global__ __launch_bounds__(256) void k_global(
    const float* __restrict__ x_aggr,
    const float* __restrict__ Wg1, const float* __restrict__ Wg2,
    const float* __restrict__ Wo1,
    float* __restrict__ g_contrib)
{
    __shared__ float sWg1[5 * HID];
    __shared__ float sWg2[HID * 4];
    __shared__ float sWo1g[4 * HID];
    for (int k = threadIdx.x; k < 5 * HID; k += 256) sWg1[k] = Wg1[k];
    for (int k = threadIdx.x; k < HID * 4; k += 256) sWg2[k] = Wg2[k];
    for (int k = threadIdx.x; k < 4 * HID; k += 256) sWo1g[k] = Wo1[5 * HID + k];
    __syncthreads();

    int bg = blockIdx.x * 256 + threadIdx.x;
    if (bg >= NUM_GRAPHS) return;

    float a[5];
#pragma unroll
    for (int c = 0; c < 5; ++c) a[c] = x_aggr[bg * 5 + c];

    float h[HID];
#pragma unroll
    for (int j = 0; j < HID; ++j) {
        float s = 0.f;
#pragma unroll
        for (int c = 0; c < 5; ++c) s += a[c] * sWg1[c * HID + j];
        h[j] = lrelu(s);
    }
    float g[4];
#pragma unroll
    for (int c = 0; c < 4; ++c) {
        float s = 0.f;
#pragma unroll
        for (int j = 0; j < HID; ++j) s += h[j] * sWg2[j * 4 + c];
        g[c] = lrelu(s);
    }
#pragma unroll
    for (int j = 0; j < HID; ++j) {
        float s = 0.f;
#pragma unroll
        for (int c = 0; c < 4; ++c) s += g[c] * sWo1g[c * HID + j];
        g_contrib[bg * HID + j] = s;
    }
}

// ---------------- Pass C: xe load (or emb fallback), h1 VALU, 40x32 MFMA, transpose-pool ----------------
__global__ __launch_bounds__(256, 3) void k_out_pool(
    const float* __restrict__ x, const int* __restrict__ batch,
    const float* __restrict__ We1, const float* __restrict__ We2,
    const float* __restrict__ Wo1, const float* __restrict__ Wo2,
    const float* __restrict__ g_contrib,
    const unsigned short* __restrict__ xe_in, int use_xe,
    float* __restrict__ pooled)
{
    // Aliased: A-staging 512 rows x 20 dw = 40960 B; xoT half-pool 16 x 516 x 4 = 33024 B.
    __shared__ __align__(16) unsigned int uLds[TILE_C * AROW];
    __shared__ __align__(16) int sb[TILE_C];
    __shared__ float sWe1[3 * HID];
    __shared__ float sWe2T[5 * HID];
    __shared__ float sWo1[5 * HID];

    int tid = threadIdx.x;
    for (int k = tid; k < 3 * HID; k += 256) sWe1[k] = We1[k];
    for (int k = tid; k < 5 * HID; k += 256) sWe2T[k] = We2[(k % HID) * 5 + k / HID];
    for (int k = tid; k < 5 * HID; k += 256) sWo1[k] = Wo1[k];

    int lane = tid & 63, wv = tid >> 6;
    int l16 = lane & 15, quad = lane >> 4;

    // B fragments (Wo2 -> bf16): lane l16 = n, k = ks*32 + quad*8 + j
    short8 bfrag[2][2];
#pragma unroll
    for (int nt = 0; nt < 2; ++nt) {
#pragma unroll
        for (int ks = 0; ks < 2; ++ks) {
#pragma unroll
            for (int j = 0; j < 8; ++j) {
                int kk = ks * 32 + quad * 8 + j;
                float w = (kk < HID) ? Wo2[kk * 32 + nt * 16 + l16] : 0.f;
                bfrag[nt][ks][j] = (short)f2bf(w);
            }
        }
    }
    short8 zfrag = {0, 0, 0, 0, 0, 0, 0, 0};
    __syncthreads();

    int base = blockIdx.x * TILE_C;

    // stage both points' h1 rows (wave-private rows -> no barrier before A-read)
#pragma unroll 1
    for (int q = 0; q < 2; ++q) {
        int p = base + q * 256 + tid;
        bool v = p < N_POINTS;
        int ic = v ? p : (N_POINTS - 1);
        int b = v ? batch[ic] : -1;
        sb[q * 256 + tid] = b;

        float xe[5];
        if (use_xe) {
#pragma unroll
            for (int c = 0; c < 5; ++c) xe[c] = bf2f(xe_in[(size_t)c * N_POINTS + ic]);
        } else {
            float x0 = x[ic * 3 + 0], x1 = x[ic * 3 + 1], x2 = x[ic * 3 + 2];
            float h[HID];
            const float4* W1r = (const float4*)sWe1;
#pragma unroll
            for (int j4 = 0; j4 < HID / 4; ++j4) {
                float4 wa = W1r[j4], wb = W1r[10 + j4], wc = W1r[20 + j4];
                float wav[4] = {wa.x, wa.y, wa.z, wa.w};
                float wbv[4] = {wb.x, wb.y, wb.z, wb.w};
                float wcv[4] = {wc.x, wc.y, wc.z, wc.w};
#pragma unroll
                for (int k = 0; k < 4; ++k)
                    h[j4 * 4 + k] = lrelu(x0 * wav[k] + x1 * wbv[k] + x2 * wcv[k]);
            }
#pragma unroll
            for (int c = 0; c < 5; ++c) {
                const float4* wr = (const float4*)&sWe2T[c * HID];
                float s = 0.f;
#pragma unroll
                for (int j4 = 0; j4 < HID / 4; ++j4) {
                    float4 w = wr[j4];
                    s += h[j4 * 4 + 0] * w.x + h[j4 * 4 + 1] * w.y + h[j4 * 4 + 2] * w.z + h[j4 * 4 + 3] * w.w;
                }
                xe[c] = lrelu(s);
            }
        }

        // h1 = lrelu(xe @ Wo1[0:5] + g_contrib[b])
        const float4* gc4 = (const float4*)(g_contrib + (size_t)(v ? b : 0) * HID);
        unsigned int* row = &uLds[(q * 256 + tid) * AROW];
#pragma unroll
        for (int j4 = 0; j4 < HID / 4; ++j4) {
            float4 g = gc4[j4];
            float sv[4] = {g.x, g.y, g.z, g.w};
#pragma unroll
            for (int c = 0; c < 5; ++c) {
                float4 w = ((const float4*)&sWo1[c * HID])[j4];
                float wvv[4] = {w.x, w.y, w.z, w.w};
#pragma unroll
                for (int k = 0; k < 4; ++k) sv[k] += xe[c] * wvv[k];
            }
            // pack 4 h1 values -> 2 dwords bf16
            __hip_bfloat162 p0 = __float22bfloat162_rn(make_float2(lrelu(sv[0]), lrelu(sv[1])));
            __hip_bfloat162 p1 = __float22bfloat162_rn(make_float2(lrelu(sv[2]), lrelu(sv[3])));
            uint2 u;
            u.x = *(unsigned int*)&p0; u.y = *(unsigned int*)&p1;
            *(uint2*)(row + j4 * 2) = u;
        }
    }

    // MFMA: wave wv owns mtiles {4wv..4wv+3} U {16+4wv..16+4wv+3}
    fx4 xov[8][2];
#pragma unroll
    for (int m = 0; m < 8; ++m) {
        int mt = (m < 4) ? (wv * 4 + m) : (16 + wv * 4 + (m - 4));
        const unsigned int* arow = &uLds[(mt * 16 + l16) * AROW];
        short8 a0 = *(const short8*)(arow + quad * 4);
        short8 a1 = (quad == 0) ? *(const short8*)(arow + 16) : zfrag;
#pragma unroll
        for (int nt = 0; nt < 2; ++nt) {
            fx4 acc = {0.f, 0.f, 0.f, 0.f};
            acc = __builtin_amdgcn_mfma_f32_16x16x32_bf16(a0, bfrag[nt][0], acc, 0, 0, 0);
            acc = __builtin_amdgcn_mfma_f32_16x16x32_bf16(a1, bfrag[nt][1], acc, 0, 0, 0);
#pragma unroll
            for (int r = 0; r < 4; ++r) acc[r] = lrelu(acc[r]);
            xov[m][nt] = acc;
        }
    }
    __syncthreads();   // all A-reads done -> safe to clobber staging with xoT

    float* xoT = (float*)uLds;
#pragma unroll 1
    for (int half = 0; half < 2; ++half) {
        // C layout: col = l16 = channel-within-half, row = quad*4+r = point
#pragma unroll
        for (int m = 0; m < 8; ++m) {
            int mt = (m < 4) ? (wv * 4 + m) : (16 + wv * 4 + (m - 4));
            int pt = mt * 16 + quad * 4;
            *(fx4*)&xoT[l16 * XOS2 + pt] = xov[m][half];
        }
        __syncthreads();

        // reduce: thread owns (ch = tid&15, chunk = tid>>4 of 32 pts)
        {
            int ch = tid & 15, chunk = tid >> 4;
            float acc = 0.f;
            int cur = sb[chunk * 32];
#pragma unroll
            for (int g = 0; g < 8; ++g) {
                float4 v4 = *(const float4*)&xoT[ch * XOS2 + chunk * 32 + g * 4];
                int4   n4 = *(const int4*)&sb[chunk * 32 + g * 4];
                float vv[4] = {v4.x, v4.y, v4.z, v4.w};
                int   nn[4] = {n4.x, n4.y, n4.z, n4.w};
#pragma unroll
                for (int k = 0; k < 4; ++k) {
                    if (nn[k] != cur) {
                        if (cur >= 0) atomicAdd(&pooled[cur * 32 + half * 16 + ch], acc);
                        cur = nn[k];
                        acc = vv[k];
                    } else {
                        acc += vv[k];
                    }
                }
            }
            if (cur >= 0) atomicAdd(&pooled[cur * 32 + half * 16 + ch], acc);
        }
        __syncthreads();
    }
}

// ---------------- Pass D: disc head per graph ----------------
__global__ __launch_bounds__(256) void k_disc(
    const float* __restrict__ pooled,
    const float* __restrict__ Wd1, const float* __restrict__ Wd2,
    float* __restrict__ out)
{
    __shared__ float sWd1T[HID * 32];  // [j][c]
    __shared__ float sWd2[HID];
    for (int k = threadIdx.x; k < 32 * HID; k += 256) sWd1T[k] = Wd1[(k % 32) * HID + k / 32];
    for (int k = threadIdx.x; k < HID; k += 256) sWd2[k] = Wd2[k];
    __syncthreads();

    int bg = blockIdx.x * 256 + threadIdx.x;
    if (bg >= NUM_GRAPHS) return;

    float p[32];
    const float4* pp = (const float4*)(pooled + (size_t)bg * 32);
#pragma unroll
    for (int c4 = 0; c4 < 8; ++c4) {
        float4 vv = pp[c4];
        p[c4 * 4 + 0] = vv.x; p[c4 * 4 + 1] = vv.y; p[c4 * 4 + 2] = vv.z; p[c4 * 4 + 3] = vv.w;
    }

    float acc = 0.f;
#pragma unroll
    for (int j = 0; j < HID; ++j) {
        const float4* wr = (const float4*)&sWd1T[j * 32];
        float s = 0.f;
#pragma unroll
        for (int c4 = 0; c4 < 8; ++c4) {
            float4 w = wr[c4];
            s += p[c4 * 4 + 0] * w.x + p[c4 * 4 + 1] * w.y + p[c4 * 4 + 2] * w.z + p[c4 * 4 + 3] * w.w;
        }
        acc += lrelu(s) * sWd2[j];
    }
    out[bg] = acc;
}

extern "C" void kernel_launch(void* const* d_in, const int* in_sizes, int n_in,
                              void* d_out, int out_size, void* d_ws, size_t ws_size,
                              hipStream_t stream) {
    const float* x     = (const float*)d_in[0];
    const int*   batch = (const int*)  d_in[1];
    const float* We1   = (const float*)d_in[2];
    const float* We2   = (const float*)d_in[3];
    const float* Wg1   = (const float*)d_in[4];
    const float* Wg2   = (const float*)d_in[5];
    const float* Wo1   = (const float*)d_in[6];
    const float* Wo2   = (const float*)d_in[7];
    const float* Wd1   = (const float*)d_in[8];
    const float* Wd2   = (const float*)d_in[9];
    float* out = (float*)d_out;

    // ws layout: [x_aggr B*5][pooled B*32][g_contrib B*40][xe bf16 planar 5*N]
    float* x_aggr    = (float*)d_ws;
    float* pooled    = x_aggr + NUM_GRAPHS * 5;
    float* g_contrib = pooled + NUM_GRAPHS * 32;
    size_t head_bytes = (size_t)NUM_GRAPHS * (5 + 32 + HID) * sizeof(float);  // 5,046,272
    unsigned short* xe_ws = (unsigned short*)((char*)d_ws + head_bytes);
    size_t need = head_bytes + (size_t)N_POINTS * 5 * sizeof(unsigned short);
    int use_xe = (ws_size >= need) ? 1 : 0;

    hipMemsetAsync(d_ws, 0, (size_t)NUM_GRAPHS * (5 + 32) * sizeof(float), stream);

    int gblk = (NUM_GRAPHS + 255) / 256;
    k_emb_aggr<<<NT_A, 256, 0, stream>>>(x, batch, We1, We2, x_aggr, xe_ws, use_xe);
    k_global <<<gblk, 256, 0, stream>>>(x_aggr, Wg1, Wg2, Wo1, g_contrib);
    k_out_pool<<<NT_C, 256, 0, stream>>>(x, batch, We1, We2, Wo1, Wo2, g_contrib,
                                         xe_ws, use_xe, pooled);
    k_disc   <<<gblk, 256, 0, stream>>>(pooled, Wd1, Wd2, out);
}

// Round 6
// 192.014 us; speedup vs baseline: 5.1820x; 5.1820x over previous
//
#include <hip/hip_runtime.h>
#include <hip/hip_bf16.h>

#define N_POINTS   2000000
#define NUM_GRAPHS 16384
#define HID        40
#define SLOPE      0.01f

// Pass A tiling: 512 pts/block, 2 pts/thread
#define TILE_A     512
#define NT_A       ((N_POINTS + TILE_A - 1) / TILE_A)   // 3907
#define XESA       584    // dwords per xeT channel row (chunk-padded max idx 571; %32==8; 16B aligned)

// Pass C tiling: 256 pts/tile, grid-stride (R4-proven)
#define TILE       256
#define NTILES     ((N_POINTS + TILE - 1) / TILE)       // 7813
#define AROW       20     // dwords per bf16 A-staging row (40 bf16)
#define XOS        260    // dwords per xoT channel row (%32==4, 16B aligned)

typedef __attribute__((ext_vector_type(8))) short short8;
typedef __attribute__((ext_vector_type(4))) float fx4;

__device__ __forceinline__ float lrelu(float v) { return v > 0.f ? v : SLOPE * v; }
__device__ __forceinline__ int padidx(int p) { return p + ((p >> 5) << 2); }  // +4 dwords per 32-chunk
__device__ __forceinline__ unsigned short f2bf(float f) {
    __hip_bfloat16 h = __float2bfloat16(f);
    return *(unsigned short*)&h;
}
__device__ __forceinline__ float bf2f(unsigned short u) {
    unsigned int v = ((unsigned int)u) << 16;
    return __uint_as_float(v);
}

// ---------------- Pass A: emb FFN (2 pts/thread) + transpose-reduce + xe bf16 cache ----------------
__global__ __launch_bounds__(256, 2) void k_emb_aggr(
    const float* __restrict__ x, const int* __restrict__ batch,
    const float* __restrict__ We1, const float* __restrict__ We2,
    float* __restrict__ x_aggr, unsigned short* __restrict__ xe_out, int use_xe)
{
    __shared__ __align__(16) float sWe1[3 * HID];
    __shared__ __align__(16) float sWe2T[5 * HID];          // [c][j]
    __shared__ __align__(16) float xeT[5 * XESA];           // chunk-padded
    __shared__ __align__(16) int   sbp[XESA];

    int tid = threadIdx.x;
    for (int k = tid; k < 3 * HID; k += 256) sWe1[k] = We1[k];
    for (int k = tid; k < 5 * HID; k += 256) sWe2T[k] = We2[(k % HID) * 5 + k / HID];
    __syncthreads();

    int base = blockIdx.x * TILE_A;
    int p0 = base + tid, p1 = base + 256 + tid;
    bool v0 = p0 < N_POINTS, v1 = p1 < N_POINTS;
    int i0 = v0 ? p0 : (N_POINTS - 1), i1 = v1 ? p1 : (N_POINTS - 1);
    float a0 = x[i0 * 3 + 0], a1 = x[i0 * 3 + 1], a2 = x[i0 * 3 + 2];
    float c0 = x[i1 * 3 + 0], c1 = x[i1 * 3 + 1], c2 = x[i1 * 3 + 2];
    int b0 = v0 ? batch[i0] : -1;
    int b1 = v1 ? batch[i1] : -1;
    sbp[padidx(tid)] = b0;
    sbp[padidx(256 + tid)] = b1;

    // layer 1: one weight read feeds 2 points
    float h0[HID], h1[HID];
    const float4* W1r = (const float4*)sWe1;
#pragma unroll
    for (int j4 = 0; j4 < HID / 4; ++j4) {
        float4 wa = W1r[j4], wb = W1r[10 + j4], wc = W1r[20 + j4];
        float wav[4] = {wa.x, wa.y, wa.z, wa.w};
        float wbv[4] = {wb.x, wb.y, wb.z, wb.w};
        float wcv[4] = {wc.x, wc.y, wc.z, wc.w};
#pragma unroll
        for (int k = 0; k < 4; ++k) {
            int j = j4 * 4 + k;
            h0[j] = lrelu(a0 * wav[k] + a1 * wbv[k] + a2 * wcv[k]);
            h1[j] = lrelu(c0 * wav[k] + c1 * wbv[k] + c2 * wcv[k]);
        }
    }

    // layer 2 + stage + bf16 cache store (fp32 goes into the aggregation)
#pragma unroll
    for (int c = 0; c < 5; ++c) {
        const float4* wr = (const float4*)&sWe2T[c * HID];
        float s0 = 0.f, s1 = 0.f;
#pragma unroll
        for (int j4 = 0; j4 < HID / 4; ++j4) {
            float4 w = wr[j4];
            float wv[4] = {w.x, w.y, w.z, w.w};
#pragma unroll
            for (int k = 0; k < 4; ++k) {
                s0 += h0[j4 * 4 + k] * wv[k];
                s1 += h1[j4 * 4 + k] * wv[k];
            }
        }
        float e0 = v0 ? lrelu(s0) : 0.f;
        float e1 = v1 ? lrelu(s1) : 0.f;
        xeT[c * XESA + padidx(tid)] = e0;
        xeT[c * XESA + padidx(256 + tid)] = e1;
        if (use_xe) {
            if (v0) xe_out[(size_t)c * N_POINTS + p0] = f2bf(e0);
            if (v1) xe_out[(size_t)c * N_POINTS + p1] = f2bf(e1);
        }
    }
    __syncthreads();

    // reduce: thread tid<80 owns (ch = tid>>4 in 0..4, chunk = tid&15 of 32 pts)
    if (tid < 80) {
        int ch = tid >> 4, chunk = tid & 15;
        float acc = 0.f;
        int cur = sbp[chunk * 36];
#pragma unroll
        for (int g = 0; g < 8; ++g) {
            float4 v4 = *(const float4*)&xeT[ch * XESA + chunk * 36 + g * 4];
            int4   n4 = *(const int4*)&sbp[chunk * 36 + g * 4];
            float vv[4] = {v4.x, v4.y, v4.z, v4.w};
            int   nn[4] = {n4.x, n4.y, n4.z, n4.w};
#pragma unroll
            for (int k = 0; k < 4; ++k) {
                if (nn[k] != cur) {
                    if (cur >= 0) atomicAdd(&x_aggr[cur * 5 + ch], acc);
                    cur = nn[k];
                    acc = vv[k];
                } else {
                    acc += vv[k];
                }
            }
        }
        if (cur >= 0) atomicAdd(&x_aggr[cur * 5 + ch], acc);
    }
}

// ---------------- Pass B: per-graph global FFN + fold into W_out1 rows 5..8 ----------------
__global__ __launch_bounds__(256) void k_global(
    const float* __restrict__ x_aggr,
    const float* __restrict__ Wg1, const float* __restrict__ Wg2,
    const float* __restrict__ Wo1,
    float* __restrict__ g_contrib)
{
    __shared__ float sWg1[5 * HID];
    __shared__ float sWg2[HID * 4];
    __shared__ float sWo1g[4 * HID];
    for (int k = threadIdx.x; k < 5 * HID; k += 256) sWg1[k] = Wg1[k];
    for (int k = threadIdx.x; k < HID * 4; k += 256) sWg2[k] = Wg2[k];
    for (int k = threadIdx.x; k < 4 * HID; k += 256) sWo1g[k] = Wo1[5 * HID + k];
    __syncthreads();

    int bg = blockIdx.x * 256 + threadIdx.x;
    if (bg >= NUM_GRAPHS) return;

    float a[5];
#pragma unroll
    for (int c = 0; c < 5; ++c) a[c] = x_aggr[bg * 5 + c];

    float h[HID];
#pragma unroll
    for (int j = 0; j < HID; ++j) {
        float s = 0.f;
#pragma unroll
        for (int c = 0; c < 5; ++c) s += a[c] * sWg1[c * HID + j];
        h[j] = lrelu(s);
    }
    float g[4];
#pragma unroll
    for (int c = 0; c < 4; ++c) {
        float s = 0.f;
#pragma unroll
        for (int j = 0; j < HID; ++j) s += h[j] * sWg2[j * 4 + c];
        g[c] = lrelu(s);
    }
#pragma unroll
    for (int j = 0; j < HID; ++j) {
        float s = 0.f;
#pragma unroll
        for (int c = 0; c < 4; ++c) s += g[c] * sWo1g[c * HID + j];
        g_contrib[bg * HID + j] = s;
    }
}

// ---------------- Pass C: xe load, h1 VALU, 40x32 bf16 MFMA, transpose-reduce pool (R4 shape) ----------------
__global__ __launch_bounds__(256, 4) void k_out_pool(
    const float* __restrict__ x, const int* __restrict__ batch,
    const float* __restrict__ We1, const float* __restrict__ We2,
    const float* __restrict__ Wo1, const float* __restrict__ Wo2,
    const float* __restrict__ g_contrib,
    const unsigned short* __restrict__ xe_in, int use_xe,
    float* __restrict__ pooled)
{
    // Aliased region: A-staging (256 rows x 20 dwords = 20480 B) then xoT (32 x 260 x 4 = 33280 B).
    __shared__ __align__(16) unsigned int uLds[32 * XOS];
    __shared__ __align__(16) int sb[TILE];
    __shared__ float sWe1[3 * HID];
    __shared__ float sWe2T[5 * HID];
    __shared__ float sWo1[5 * HID];

    int tid = threadIdx.x;
    for (int k = tid; k < 3 * HID; k += 256) sWe1[k] = We1[k];
    for (int k = tid; k < 5 * HID; k += 256) sWe2T[k] = We2[(k % HID) * 5 + k / HID];
    for (int k = tid; k < 5 * HID; k += 256) sWo1[k] = Wo1[k];

    int lane = tid & 63;
    int l16 = lane & 15, quad = lane >> 4;

    // B fragments (Wo2 -> bf16), built once: lane l16 = n, k = ks*32 + quad*8 + j
    short8 bfrag[2][2];
#pragma unroll
    for (int nt = 0; nt < 2; ++nt) {
#pragma unroll
        for (int ks = 0; ks < 2; ++ks) {
#pragma unroll
            for (int j = 0; j < 8; ++j) {
                int kk = ks * 32 + quad * 8 + j;
                float w = (kk < HID) ? Wo2[kk * 32 + nt * 16 + l16] : 0.f;
                bfrag[nt][ks][j] = (short)f2bf(w);
            }
        }
    }
    short8 zfrag = {0, 0, 0, 0, 0, 0, 0, 0};
    __syncthreads();

    for (int t = blockIdx.x; t < NTILES; t += gridDim.x) {
        int i = t * TILE + tid;
        bool v = i < N_POINTS;
        int ic = v ? i : (N_POINTS - 1);
        int b = v ? batch[ic] : -1;
        sb[tid] = b;

        float xe[5];
        if (use_xe) {
#pragma unroll
            for (int c = 0; c < 5; ++c) xe[c] = bf2f(xe_in[(size_t)c * N_POINTS + ic]);
        } else {
            float x0 = x[ic * 3 + 0], x1 = x[ic * 3 + 1], x2 = x[ic * 3 + 2];
            float h[HID];
            const float4* W1r = (const float4*)sWe1;
#pragma unroll
            for (int j4 = 0; j4 < HID / 4; ++j4) {
                float4 wa = W1r[j4], wb = W1r[10 + j4], wc = W1r[20 + j4];
                float wav[4] = {wa.x, wa.y, wa.z, wa.w};
                float wbv[4] = {wb.x, wb.y, wb.z, wb.w};
                float wcv[4] = {wc.x, wc.y, wc.z, wc.w};
#pragma unroll
                for (int k = 0; k < 4; ++k)
                    h[j4 * 4 + k] = lrelu(x0 * wav[k] + x1 * wbv[k] + x2 * wcv[k]);
            }
#pragma unroll
            for (int c = 0; c < 5; ++c) {
                const float4* wr = (const float4*)&sWe2T[c * HID];
                float s = 0.f;
#pragma unroll
                for (int j4 = 0; j4 < HID / 4; ++j4) {
                    float4 w = wr[j4];
                    s += h[j4 * 4 + 0] * w.x + h[j4 * 4 + 1] * w.y + h[j4 * 4 + 2] * w.z + h[j4 * 4 + 3] * w.w;
                }
                xe[c] = lrelu(s);
            }
        }

        // h1 = lrelu(xe @ Wo1[0:5] + g_contrib[b]); pack bf16; stage A row (wave-private rows)
        const float4* gc4 = (const float4*)(g_contrib + (size_t)(v ? b : 0) * HID);
        unsigned int* row = &uLds[tid * AROW];
#pragma unroll
        for (int j4 = 0; j4 < HID / 4; ++j4) {
            float4 g = gc4[j4];
            float sv[4] = {g.x, g.y, g.z, g.w};
#pragma unroll
            for (int c = 0; c < 5; ++c) {
                float4 w = ((const float4*)&sWo1[c * HID])[j4];
                float wvv[4] = {w.x, w.y, w.z, w.w};
#pragma unroll
                for (int k = 0; k < 4; ++k) sv[k] += xe[c] * wvv[k];
            }
            __hip_bfloat162 q0 = __float22bfloat162_rn(make_float2(lrelu(sv[0]), lrelu(sv[1])));
            __hip_bfloat162 q1 = __float22bfloat162_rn(make_float2(lrelu(sv[2]), lrelu(sv[3])));
            uint2 u;
            u.x = *(unsigned int*)&q0; u.y = *(unsigned int*)&q1;
            *(uint2*)(row + j4 * 2) = u;
        }

        // MFMA: wave owns mtiles 4w..4w+3; 2 ntiles; K = 32 + 8 (second frag zero for quad>0)
        fx4 xov[4][2];
#pragma unroll
        for (int m = 0; m < 4; ++m) {
            int mt = (tid >> 6) * 4 + m;
            const unsigned int* arow = &uLds[(mt * 16 + l16) * AROW];
            short8 a0 = *(const short8*)(arow + quad * 4);
            short8 a1 = (quad == 0) ? *(const short8*)(arow + 16) : zfrag;
#pragma unroll
            for (int nt = 0; nt < 2; ++nt) {
                fx4 acc = {0.f, 0.f, 0.f, 0.f};
                acc = __builtin_amdgcn_mfma_f32_16x16x32_bf16(a0, bfrag[nt][0], acc, 0, 0, 0);
                acc = __builtin_amdgcn_mfma_f32_16x16x32_bf16(a1, bfrag[nt][1], acc, 0, 0, 0);
#pragma unroll
                for (int r = 0; r < 4; ++r) acc[r] = lrelu(acc[r]);
                xov[m][nt] = acc;
            }
        }
        __syncthreads();   // all A-frag reads done -> safe to clobber staging with xoT

        // C layout: col = l16 = channel, row = quad*4 + r = point -> float4 of 4 consecutive pts
        float* xoT = (float*)uLds;
#pragma unroll
        for (int m = 0; m < 4; ++m) {
            int mt = (tid >> 6) * 4 + m;
#pragma unroll
            for (int nt = 0; nt < 2; ++nt) {
                int ch = nt * 16 + l16;
                int pt = mt * 16 + quad * 4;
                *(fx4*)&xoT[ch * XOS + pt] = xov[m][nt];
            }
        }
        __syncthreads();

        // chunk-reduce: thread owns (ch = tid&31, 32-pt chunk = tid>>5)
        {
            int ch = tid & 31, chunk = tid >> 5;
            float acc = 0.f;
            int cur = sb[chunk * 32];
#pragma unroll
            for (int g = 0; g < 8; ++g) {
                float4 v4 = *(const float4*)&xoT[ch * XOS + chunk * 32 + g * 4];
                int4   n4 = *(const int4*)&sb[chunk * 32 + g * 4];
                float vv[4] = {v4.x, v4.y, v4.z, v4.w};
                int   nn[4] = {n4.x, n4.y, n4.z, n4.w};
#pragma unroll
                for (int k = 0; k < 4; ++k) {
                    if (nn[k] != cur) {
                        if (cur >= 0) atomicAdd(&pooled[cur * 32 + ch], acc);
                        cur = nn[k];
                        acc = vv[k];
                    } else {
                        acc += vv[k];
                    }
                }
            }
            if (cur >= 0) atomicAdd(&pooled[cur * 32 + ch], acc);
        }
        __syncthreads();   // reduce reads done -> next tile may restage
    }
}

// ---------------- Pass D: disc head per graph ----------------
__global__ __launch_bounds__(256) void k_disc(
    const float* __restrict__ pooled,
    const float* __restrict__ Wd1, const float* __restrict__ Wd2,
    float* __restrict__ out)
{
    __shared__ float sWd1T[HID * 32];  // [j][c]
    __shared__ float sWd2[HID];
    for (int k = threadIdx.x; k < 32 * HID; k += 256) sWd1T[k] = Wd1[(k % 32) * HID + k / 32];
    for (int k = threadIdx.x; k < HID; k += 256) sWd2[k] = Wd2[k];
    __syncthreads();

    int bg = blockIdx.x * 256 + threadIdx.x;
    if (bg >= NUM_GRAPHS) return;

    float p[32];
    const float4* pp = (const float4*)(pooled + (size_t)bg * 32);
#pragma unroll
    for (int c4 = 0; c4 < 8; ++c4) {
        float4 vv = pp[c4];
        p[c4 * 4 + 0] = vv.x; p[c4 * 4 + 1] = vv.y; p[c4 * 4 + 2] = vv.z; p[c4 * 4 + 3] = vv.w;
    }

    float acc = 0.f;
#pragma unroll
    for (int j = 0; j < HID; ++j) {
        const float4* wr = (const float4*)&sWd1T[j * 32];
        float s = 0.f;
#pragma unroll
        for (int c4 = 0; c4 < 8; ++c4) {
            float4 w = wr[c4];
            s += p[c4 * 4 + 0] * w.x + p[c4 * 4 + 1] * w.y + p[c4 * 4 + 2] * w.z + p[c4 * 4 + 3] * w.w;
        }
        acc += lrelu(s) * sWd2[j];
    }
    out[bg] = acc;
}

extern "C" void kernel_launch(void* const* d_in, const int* in_sizes, int n_in,
                              void* d_out, int out_size, void* d_ws, size_t ws_size,
                              hipStream_t stream) {
    const float* x     = (const float*)d_in[0];
    const int*   batch = (const int*)  d_in[1];
    const float* We1   = (const float*)d_in[2];
    const float* We2   = (const float*)d_in[3];
    const float* Wg1   = (const float*)d_in[4];
    const float* Wg2   = (const float*)d_in[5];
    const float* Wo1   = (const float*)d_in[6];
    const float* Wo2   = (const float*)d_in[7];
    const float* Wd1   = (const float*)d_in[8];
    const float* Wd2   = (const float*)d_in[9];
    float* out = (float*)d_out;

    // ws layout: [x_aggr B*5][pooled B*32][g_contrib B*40][xe bf16 planar 5*N]
    float* x_aggr    = (float*)d_ws;
    float* pooled    = x_aggr + NUM_GRAPHS * 5;
    float* g_contrib = pooled + NUM_GRAPHS * 32;
    size_t head_bytes = (size_t)NUM_GRAPHS * (5 + 32 + HID) * sizeof(float);
    unsigned short* xe_ws = (unsigned short*)((char*)d_ws + head_bytes);
    size_t need = head_bytes + (size_t)N_POINTS * 5 * sizeof(unsigned short);
    int use_xe = (ws_size >= need) ? 1 : 0;

    hipMemsetAsync(d_ws, 0, (size_t)NUM_GRAPHS * (5 + 32) * sizeof(float), stream);

    int gblk = (NUM_GRAPHS + 255) / 256;
    k_emb_aggr<<<NT_A, 256, 0, stream>>>(x, batch, We1, We2, x_aggr, xe_ws, use_xe);
    k_global <<<gblk, 256, 0, stream>>>(x_aggr, Wg1, Wg2, Wo1, g_contrib);
    k_out_pool<<<1024, 256, 0, stream>>>(x, batch, We1, We2, Wo1, Wo2, g_contrib,
                                         xe_ws, use_xe, pooled);
    k_disc   <<<gblk, 256, 0, stream>>>(pooled, Wd1, Wd2, out);
}